// Round 6
// baseline (316.397 us; speedup 1.0000x reference)
//
#include <hip/hip_runtime.h>
#include <stdint.h>

#define NH 16
#define DH 64
#define DM 1024
#define Bz 4
#define Sz 2048
#define NKT 16   // K tiles of 64 in DM

typedef __bf16 bf16x8 __attribute__((ext_vector_type(8)));
typedef float f32x4 __attribute__((ext_vector_type(4)));

// async global(16B/lane) -> LDS (wave-uniform base + lane*16)
#define GLD_LDS16(gsrc, ldst)                                             \
    __builtin_amdgcn_global_load_lds(                                     \
        (const __attribute__((address_space(1))) void*)(gsrc),            \
        (__attribute__((address_space(3))) void*)(ldst), 16, 0, 0)

__device__ __forceinline__ unsigned short f2bf(float f) {
    unsigned u = __float_as_uint(f);
    u += 0x7FFFu + ((u >> 16) & 1u);          // RNE
    return (unsigned short)(u >> 16);
}
__device__ __forceinline__ float bf2f(unsigned short h) {
    return __uint_as_float(((unsigned)h) << 16);
}

// ---------------------------------------------------------------------------
// Dtype detection (f32 vs bf16 storage). flag=1 => f32.
// ---------------------------------------------------------------------------
__global__ void detect_dtype(const unsigned short* __restrict__ xs,
                             int* __restrict__ flagp)
{
    const int t = threadIdx.x;          // 64 threads, 1 block
    int cnt = 0;
    for (int i = 0; i < 64; i++) {
        const unsigned short h = xs[(t * 64 + i) * 2];
        const int e = (h >> 7) & 0xFF;
        if (h != 0 && e >= 100 && e <= 130) cnt++;
    }
#pragma unroll
    for (int off = 32; off >= 1; off >>= 1)
        cnt += __shfl_xor(cnt, off);
    if (t == 0) *flagp = (cnt < 2048) ? 1 : 0;
}

// ---------------------------------------------------------------------------
// Canonicalize 9 tensors into bf16 workspace buffers.
// ---------------------------------------------------------------------------
__global__ __launch_bounds__(256) void convert_inputs(
    const void* s0, const void* s1, const void* s2, const void* s3,
    const void* s4, const void* s5, const void* s6, const void* s7,
    const void* s8,
    unsigned short* d0, unsigned short* d1, unsigned short* d2,
    unsigned short* d3, unsigned short* d4, unsigned short* d5,
    unsigned short* d6, unsigned short* d7, unsigned short* d8,
    const int* __restrict__ flagp)
{
    const void* s; unsigned short* d; int n;
    switch (blockIdx.y) {
        case 0: s = s0; d = d0; n = Bz * Sz * DM; break;   // x
        case 1: s = s1; d = d1; n = DM * DM; break;        // Wq
        case 2: s = s2; d = d2; n = DM * DM; break;        // Wk
        case 3: s = s3; d = d3; n = DM * DM; break;        // Wv
        case 4: s = s4; d = d4; n = DM * DM; break;        // Wo
        case 5: s = s5; d = d5; n = DM; break;             // bq
        case 6: s = s6; d = d6; n = DM; break;             // bk
        case 7: s = s7; d = d7; n = DM; break;             // bv
        default: s = s8; d = d8; n = DM; break;            // bo
    }
    const int flag   = *flagp;
    const int stride = gridDim.x * blockDim.x * 4;
    const int base   = (blockIdx.x * blockDim.x + threadIdx.x) * 4;
    if (flag) {
        const float* sf = (const float*)s;
        for (int i = base; i < n; i += stride) {
            const float4 v = *reinterpret_cast<const float4*>(&sf[i]);
            ushort2 a, b;
            a.x = f2bf(v.x); a.y = f2bf(v.y);
            b.x = f2bf(v.z); b.y = f2bf(v.w);
            *reinterpret_cast<ushort2*>(&d[i])     = a;
            *reinterpret_cast<ushort2*>(&d[i + 2]) = b;
        }
    } else {
        const unsigned short* sh = (const unsigned short*)s;
        for (int i = base; i < n; i += stride)
            *reinterpret_cast<uint2*>(&d[i]) = *reinterpret_cast<const uint2*>(&sh[i]);
    }
}

// ===========================================================================
// R10: 256x256-tile 8-wave GEMM body (shared by gemm_qkv / gemm_out).
//
// Evidence: R0/R2/R5 all ~98-101us at MfmaUtil 21% (schedule-invariant);
// FETCH halved (R5) with no speedup => 64x64-wave-tile 2-phase structure is
// the wall (32 FLOP/LDS-byte ~ LDS-port roofline; + measured 1.5x read
// conflicts at 64B row stride). This template: 128x64 wave tiles
// (43 FLOP/B), XOR-swizzled conflict-free LDS (T2, both-sides per T21:
// pre-swizzled per-lane global src + linear gld_lds dst + swizzled ds_read),
// full double-buffer (128KB LDS), depth-1 prefetch (per-tile MFMA ~1240cy
// >> ~400cy L2 latency), ONE vmcnt(0)+s_barrier per K-tile (stage targets
// the idle buffer: no intra-tile WAR, no phase barriers), setprio(T5).
//
// Layout invariants carried over from the verified 128-tile kernel:
//   frag A row=m, frag B row=n, k-elem = slab*32 + quad*8;
//   C: row = quad*4+r (m), col = l15 (n).
// ===========================================================================

// swizzled LDS read of one bf16x8 fragment; lds is element pointer to the
// current buffer base; R = local row (0..255), c = column byte (quad*16+slab*64)
__device__ __forceinline__ bf16x8 lds_frag(const unsigned short* lds, int R, int c) {
    const int cs = c ^ ((R & 7) << 4);
    return *reinterpret_cast<const bf16x8*>(
        reinterpret_cast<const char*>(lds) + R * 128 + cs);
}

// ---------------------------------------------------------------------------
// QKV projection: C = X[8192,1024] @ W[1024,1024]^T + b, scattered to
// Q,K: [b*16+h][s][64]  and  Vt: [b*16+h][d][s]   (all bf16)
// grid: 384 blocks x 512 threads. XCD remap: k8 owns M-chunk [k8*1024,+1024);
// proj-outer (resident set ~ X-chunk 2MB + W-proj 2MB).
// ---------------------------------------------------------------------------
__global__ __launch_bounds__(512, 2) void gemm_qkv(
    const unsigned short* __restrict__ X,
    const unsigned short* __restrict__ Wq,
    const unsigned short* __restrict__ Wk,
    const unsigned short* __restrict__ Wv,
    const unsigned short* __restrict__ bq,
    const unsigned short* __restrict__ bk,
    const unsigned short* __restrict__ bv,
    unsigned short* __restrict__ Qb,
    unsigned short* __restrict__ Kb,
    unsigned short* __restrict__ Vtb)
{
    __shared__ __align__(16) unsigned short Alds[2][256 * 64];   // 64 KB
    __shared__ __align__(16) unsigned short Blds[2][256 * 64];   // 64 KB

    const int tid  = threadIdx.x;
    const int w    = tid >> 6, lane = tid & 63;
    const int quad = lane >> 4, l15 = lane & 15;
    const int wr   = w >> 2, wc = w & 3;          // 2M x 4N wave grid

    // XCD remap: flat -> (proj, bm, bn). 384 = 8 XCD x (3 proj x 16)
    const int flat = (int)blockIdx.x;             // 0..383
    const int k8   = flat & 7;
    const int m    = flat >> 3;                   // 0..47
    const int proj = m >> 4;                      // 0..2
    const int mm   = m & 15;                      // 0..15
    const int bm   = (k8 * 4 + (mm >> 2)) * 256;  // 0..7936
    const int bn   = (mm & 3) * 256;              // 0..768

    const unsigned short* W      = proj == 0 ? Wq : (proj == 1 ? Wk : Wv);
    const unsigned short* bias_p = proj == 0 ? bq : (proj == 1 ? bk : bv);
    const unsigned short* Abase  = X + (size_t)bm * DM;
    const unsigned short* Bbase  = W + (size_t)bn * DM;

    // staging geometry: thread t covers lds row (8*w + (lane>>3)) + 64*q,
    // col bytes (lane&7)*16; global source column pre-swizzled (T21).
    const int srow = 8 * w + (lane >> 3);         // 0..63
    const int scb  = (lane & 7) * 16;             // 0..112
    const int ssc  = scb ^ ((srow & 7) << 4);     // swizzled col byte (r and r+64/r+128 share r&7.. (srow+64)&7==srow&7? 64%8==0 yes)

    f32x4 acc[8][4];
#pragma unroll
    for (int i = 0; i < 8; i++)
#pragma unroll
        for (int j = 0; j < 4; j++)
            acc[i][j] = f32x4{0.f, 0.f, 0.f, 0.f};

    auto stage_tile = [&](int buf, int kt) {
        const int kc = kt * 64;                   // element col base
#pragma unroll
        for (int q = 0; q < 2; q++) {
            const int r  = srow + 64 * q;         // 0..127 ; (r&7)==(srow&7)
            const int ld = (64 * q + 8 * w) * 64; // lds element offset (wave-uniform)
            GLD_LDS16(&Abase[(size_t)(r      ) * DM + kc + (ssc >> 1)], &Alds[buf][ld]);
            GLD_LDS16(&Abase[(size_t)(r + 128) * DM + kc + (ssc >> 1)], &Alds[buf][ld + 128 * 64]);
            GLD_LDS16(&Bbase[(size_t)(r      ) * DM + kc + (ssc >> 1)], &Blds[buf][ld]);
            GLD_LDS16(&Bbase[(size_t)(r + 128) * DM + kc + (ssc >> 1)], &Blds[buf][ld + 128 * 64]);
        }
    };

    // prologue
    stage_tile(0, 0);
    asm volatile("s_waitcnt vmcnt(0)" ::: "memory");
    __builtin_amdgcn_s_barrier();
    asm volatile("" ::: "memory");

    for (int T = 0; T < NKT; ++T) {
        const int cur = T & 1;
        if (T < NKT - 1) stage_tile(cur ^ 1, T + 1);

        const unsigned short* A = &Alds[cur][0];
        const unsigned short* B = &Blds[cur][0];
        const int aR0 = wr * 128 + l15;           // + mi*16
        const int bR0 = wc * 64 + l15;            // + nj*16

        bf16x8 aR[4][2], b01[2][2], b23[2][2];
        // phase 1: A(m0-3) + B(n0-1), MFMA quadrant 00
#pragma unroll
        for (int mi = 0; mi < 4; mi++) {
            aR[mi][0] = lds_frag(A, aR0 + mi * 16, quad * 16);
            aR[mi][1] = lds_frag(A, aR0 + mi * 16, quad * 16 + 64);
        }
#pragma unroll
        for (int nj = 0; nj < 2; nj++) {
            b01[nj][0] = lds_frag(B, bR0 + nj * 16, quad * 16);
            b01[nj][1] = lds_frag(B, bR0 + nj * 16, quad * 16 + 64);
        }
        __builtin_amdgcn_s_setprio(1);
#pragma unroll
        for (int mi = 0; mi < 4; mi++)
#pragma unroll
            for (int nj = 0; nj < 2; nj++) {
                acc[mi][nj] = __builtin_amdgcn_mfma_f32_16x16x32_bf16(aR[mi][0], b01[nj][0], acc[mi][nj], 0, 0, 0);
                acc[mi][nj] = __builtin_amdgcn_mfma_f32_16x16x32_bf16(aR[mi][1], b01[nj][1], acc[mi][nj], 0, 0, 0);
            }
        __builtin_amdgcn_s_setprio(0);
        // phase 2: B(n2-3), MFMA quadrant 01
#pragma unroll
        for (int nj = 0; nj < 2; nj++) {
            b23[nj][0] = lds_frag(B, bR0 + (nj + 2) * 16, quad * 16);
            b23[nj][1] = lds_frag(B, bR0 + (nj + 2) * 16, quad * 16 + 64);
        }
        __builtin_amdgcn_s_setprio(1);
#pragma unroll
        for (int mi = 0; mi < 4; mi++)
#pragma unroll
            for (int nj = 0; nj < 2; nj++) {
                acc[mi][nj + 2] = __builtin_amdgcn_mfma_f32_16x16x32_bf16(aR[mi][0], b23[nj][0], acc[mi][nj + 2], 0, 0, 0);
                acc[mi][nj + 2] = __builtin_amdgcn_mfma_f32_16x16x32_bf16(aR[mi][1], b23[nj][1], acc[mi][nj + 2], 0, 0, 0);
            }
        __builtin_amdgcn_s_setprio(0);
        // phase 3: A(m4-7), MFMA quadrant 11
#pragma unroll
        for (int mi = 0; mi < 4; mi++) {
            aR[mi][0] = lds_frag(A, aR0 + (mi + 4) * 16, quad * 16);
            aR[mi][1] = lds_frag(A, aR0 + (mi + 4) * 16, quad * 16 + 64);
        }
        __builtin_amdgcn_s_setprio(1);
#pragma unroll
        for (int mi = 0; mi < 4; mi++)
#pragma unroll
            for (int nj = 0; nj < 2; nj++) {
                acc[mi + 4][nj + 2] = __builtin_amdgcn_mfma_f32_16x16x32_bf16(aR[mi][0], b23[nj][0], acc[mi + 4][nj + 2], 0, 0, 0);
                acc[mi + 4][nj + 2] = __builtin_amdgcn_mfma_f32_16x16x32_bf16(aR[mi][1], b23[nj][1], acc[mi + 4][nj + 2], 0, 0, 0);
            }
        // phase 4: pure-reg MFMA quadrant 10 (A4-7 x B0-1); hides stage latency
#pragma unroll
        for (int mi = 0; mi < 4; mi++)
#pragma unroll
            for (int nj = 0; nj < 2; nj++) {
                acc[mi + 4][nj] = __builtin_amdgcn_mfma_f32_16x16x32_bf16(aR[mi][0], b01[nj][0], acc[mi + 4][nj], 0, 0, 0);
                acc[mi + 4][nj] = __builtin_amdgcn_mfma_f32_16x16x32_bf16(aR[mi][1], b01[nj][1], acc[mi + 4][nj], 0, 0, 0);
            }
        __builtin_amdgcn_s_setprio(0);

        asm volatile("s_waitcnt vmcnt(0)" ::: "memory");
        __builtin_amdgcn_s_barrier();
        asm volatile("" ::: "memory");
    }

    // epilogue: C row = bm + wr*128 + mi*16 + quad*4 + r ; col = bn + wc*64 + nj*16 + l15
    if (proj < 2) {
        unsigned short* dst = (proj == 0) ? Qb : Kb;
#pragma unroll
        for (int nj = 0; nj < 4; nj++) {
            const int   e    = bn + wc * 64 + nj * 16 + l15;
            const int   h    = e >> 6, dd = e & 63;
            const float bias = bf2f(bias_p[e]);
#pragma unroll
            for (int mi = 0; mi < 8; mi++) {
#pragma unroll
                for (int r = 0; r < 4; r++) {
                    const int mrow = bm + wr * 128 + mi * 16 + quad * 4 + r;
                    const int b = mrow >> 11, s = mrow & 2047;
                    dst[((size_t)(b * NH + h) * Sz + s) * DH + dd] = f2bf(acc[mi][nj][r] + bias);
                }
            }
        }
    } else {
#pragma unroll
        for (int nj = 0; nj < 4; nj++) {
            const int   e    = bn + wc * 64 + nj * 16 + l15;
            const int   h    = e >> 6, dd = e & 63;
            const float bias = bf2f(bias_p[e]);
#pragma unroll
            for (int mi = 0; mi < 8; mi++) {
                const int m0 = bm + wr * 128 + mi * 16 + quad * 4;   // s-aligned to 4
                const int b  = m0 >> 11, s0 = m0 & 2047;
                const unsigned u0 = __float_as_uint(acc[mi][nj][0] + bias) + 0x8000u;
                const unsigned u1 = __float_as_uint(acc[mi][nj][1] + bias) + 0x8000u;
                const unsigned u2 = __float_as_uint(acc[mi][nj][2] + bias) + 0x8000u;
                const unsigned u3 = __float_as_uint(acc[mi][nj][3] + bias) + 0x8000u;
                uint2 pk;
                pk.x = __builtin_amdgcn_perm(u1, u0, 0x07060302u);
                pk.y = __builtin_amdgcn_perm(u3, u2, 0x07060302u);
                *reinterpret_cast<uint2*>(
                    &Vtb[((size_t)(b * NH + h) * DH + dd) * Sz + s0]) = pk;
            }
        }
    }
}

// ---------------------------------------------------------------------------
// Flash attention — UNCHANGED from the R5-passing version.
// ---------------------------------------------------------------------------
__global__ __launch_bounds__(512) void flash_attn(
    const unsigned short* __restrict__ Qb,    // [64][2048][64]
    const unsigned short* __restrict__ Kb,    // [64][2048][64]
    const unsigned short* __restrict__ Vtb,   // [64][64][2048]
    unsigned short* __restrict__ AOb)         // [4][2048][1024]
{
    __shared__ __align__(16) unsigned short Ks[64 * 72];    // [kv][d]
    __shared__ __align__(16) unsigned short Vs[64 * 72];    // [d][kv]
    __shared__ __align__(16) unsigned short Ps[128 * 72];   // [q][kv], wave-private rows

    const int tid  = threadIdx.x;
    const int w    = tid >> 6, lane = tid & 63;
    const int quad = lane >> 4, l15 = lane & 15;

    // XCD-locality remap: flat -> (bh, cA); bh % 8 == XCD id
    const int flat = (int)(blockIdx.y * gridDim.x + blockIdx.x);  // 0..511
    const int k8   = flat & 7;
    const int m    = flat >> 3;          // 0..63
    const int bh   = k8 + 8 * (m >> 3);  // 8 heads per XCD
    const int cA   = m & 7;

    const int srow = tid >> 3;            // 0..63  (512 threads)
    const int scc  = (tid & 7) * 8;       // 0..56
    const int hh = bh & 15, bb = bh >> 4;

    for (int pass = 0; pass < 2; pass++) {
        const int chunk = pass ? (15 - cA) : cA;
        const int qb = chunk * 128;
        const int qw = qb + w * 16;                  // wave's 16 q rows

        // Q fragment: B-operand layout (row=q=l15, k=quad*8+j)
        const size_t qbase = ((size_t)bh * Sz + qw + l15) * DH;
        const bf16x8 qf0 = *reinterpret_cast<const bf16x8*>(&Qb[qbase + quad * 8]);
        const bf16x8 qf1 = *reinterpret_cast<const bf16x8*>(&Qb[qbase + 32 + quad * 8]);

        f32x4 o[4];
#pragma unroll
        for (int jd = 0; jd < 4; jd++) o[jd] = f32x4{0.f, 0.f, 0.f, 0.f};
        float lsum = 0.f;

        const int n_kv = qb + 128;                   // multiple of 128

        auto compute = [&](int kb) {
            const bool need_mask = (kb + 64 > qw);
#pragma unroll
            for (int j = 0; j < 4; j++) {
                const bf16x8 kf0 = *reinterpret_cast<const bf16x8*>(&Ks[(j * 16 + l15) * 72 + quad * 8]);
                const bf16x8 kf1 = *reinterpret_cast<const bf16x8*>(&Ks[(j * 16 + l15) * 72 + 32 + quad * 8]);
                f32x4 st = f32x4{0.f, 0.f, 0.f, 0.f};
                st = __builtin_amdgcn_mfma_f32_16x16x32_bf16(kf0, qf0, st, 0, 0, 0);
                st = __builtin_amdgcn_mfma_f32_16x16x32_bf16(kf1, qf1, st, 0, 0, 0);
                // p = exp(S/8) = exp2(S * 0.125*log2(e)); causal mask via select
                const int qa = qw + l15;
                float p[4];
#pragma unroll
                for (int r = 0; r < 4; r++) {
                    float e = __builtin_amdgcn_exp2f(st[r] * 0.18033688011f);
                    if (need_mask) {
                        const int kv = kb + j * 16 + quad * 4 + r;
                        e = (kv <= qa) ? e : 0.f;
                    }
                    p[r] = e;
                }
                lsum += (p[0] + p[1]) + (p[2] + p[3]);
                const unsigned u0 = __float_as_uint(p[0]) + 0x8000u;
                const unsigned u1 = __float_as_uint(p[1]) + 0x8000u;
                const unsigned u2 = __float_as_uint(p[2]) + 0x8000u;
                const unsigned u3 = __float_as_uint(p[3]) + 0x8000u;
                const unsigned pk0 = __builtin_amdgcn_perm(u1, u0, 0x07060302u);
                const unsigned pk1 = __builtin_amdgcn_perm(u3, u2, 0x07060302u);
                const int prow = (w * 16 + l15) * 72 + j * 16 + quad * 4;
                *reinterpret_cast<unsigned*>(&Ps[prow])     = pk0;
                *reinterpret_cast<unsigned*>(&Ps[prow + 2]) = pk1;
            }

            // wave-private Ps rows: in-wave drain only, no barrier
            asm volatile("s_waitcnt lgkmcnt(0)" ::: "memory");

            const bf16x8 pf0 = *reinterpret_cast<const bf16x8*>(&Ps[(w * 16 + l15) * 72 + quad * 8]);
            const bf16x8 pf1 = *reinterpret_cast<const bf16x8*>(&Ps[(w * 16 + l15) * 72 + 32 + quad * 8]);
#pragma unroll
            for (int jd = 0; jd < 4; jd++) {
                const bf16x8 vf0 = *reinterpret_cast<const bf16x8*>(&Vs[(jd * 16 + l15) * 72 + quad * 8]);
                const bf16x8 vf1 = *reinterpret_cast<const bf16x8*>(&Vs[(jd * 16 + l15) * 72 + 32 + quad * 8]);
                o[jd] = __builtin_amdgcn_mfma_f32_16x16x32_bf16(pf0, vf0, o[jd], 0, 0, 0);
                o[jd] = __builtin_amdgcn_mfma_f32_16x16x32_bf16(pf1, vf1, o[jd], 0, 0, 0);
            }
        };

        // prologue: prefetch tile 0 into registers
        uint4 kr0 = *reinterpret_cast<const uint4*>(&Kb[((size_t)bh * Sz + srow) * DH + scc]);
        uint4 vr0 = *reinterpret_cast<const uint4*>(&Vtb[((size_t)bh * DH + srow) * Sz + scc]);
        uint4 kr1, vr1;

        for (int kb = 0; kb < n_kv; kb += 128) {
            // ---------------- tile kb (regs kr0/vr0) ----------------
            __syncthreads();    // prev compute done; drains kr0/vr0 (used now)
            *reinterpret_cast<uint4*>(&Ks[srow * 72 + scc]) = kr0;
            *reinterpret_cast<uint4*>(&Vs[srow * 72 + scc]) = vr0;
            // prefetch tile kb+64 (always exists: n_kv is a multiple of 128)
            kr1 = *reinterpret_cast<const uint4*>(&Kb[((size_t)bh * Sz + kb + 64 + srow) * DH + scc]);
            vr1 = *reinterpret_cast<const uint4*>(&Vtb[((size_t)bh * DH + srow) * Sz + kb + 64 + scc]);
            asm volatile("s_waitcnt lgkmcnt(0)" ::: "memory");
            __builtin_amdgcn_s_barrier();             // raw: keep prefetch in flight
            asm volatile("" ::: "memory");
            if (kb <= qw + 15) compute(kb);

            // ---------------- tile kb+64 (regs kr1/vr1) ----------------
            __syncthreads();
            *reinterpret_cast<uint4*>(&Ks[srow * 72 + scc]) = kr1;
            *reinterpret_cast<uint4*>(&Vs[srow * 72 + scc]) = vr1;
            if (kb + 128 < n_kv) {
                kr0 = *reinterpret_cast<const uint4*>(&Kb[((size_t)bh * Sz + kb + 128 + srow) * DH + scc]);
                vr0 = *reinterpret_cast<const uint4*>(&Vtb[((size_t)bh * DH + srow) * Sz + kb + 128 + scc]);
            }
            asm volatile("s_waitcnt lgkmcnt(0)" ::: "memory");
            __builtin_amdgcn_s_barrier();
            asm volatile("" ::: "memory");
            if (kb + 64 <= qw + 15) compute(kb + 64);
        }

        // reduce lsum across quads (lane holds partial for q = qw + l15)
        lsum += __shfl_xor(lsum, 16);
        lsum += __shfl_xor(lsum, 32);

        // write AO[b][s][h*64+d]; o[jd][r] is q-row quad*4+r, col jd*16+l15
        float linv[4];
#pragma unroll
        for (int r = 0; r < 4; r++)
            linv[r] = 1.0f / __shfl(lsum, quad * 4 + r);
#pragma unroll
        for (int jd = 0; jd < 4; jd++) {
#pragma unroll
            for (int r = 0; r < 4; r++) {
                const int s = qw + quad * 4 + r;
                AOb[((size_t)(bb * Sz + s)) * DM + hh * DH + jd * 16 + l15] =
                    f2bf(o[jd][r] * linv[r]);
            }
        }
    }
}

// ---------------------------------------------------------------------------
// Output projection: out = AO[8192,1024] @ Wo[1024,1024]^T + bo
// R10: same 256^2 8-wave template. grid: 128 blocks x 512 threads.
// XCD remap: k8 owns M-chunk [k8*1024,+1024) (A 2MB + Wo 2MB resident).
// ---------------------------------------------------------------------------
__global__ __launch_bounds__(512, 2) void gemm_out(
    const unsigned short* __restrict__ Ain,
    const unsigned short* __restrict__ W,
    const unsigned short* __restrict__ bo,
    void* __restrict__ outv,
    const int* __restrict__ flagp)
{
    __shared__ __align__(16) unsigned short Alds[2][256 * 64];
    __shared__ __align__(16) unsigned short Blds[2][256 * 64];

    const int tid  = threadIdx.x;
    const int w    = tid >> 6, lane = tid & 63;
    const int quad = lane >> 4, l15 = lane & 15;
    const int wr   = w >> 2, wc = w & 3;

    // XCD remap: 128 = 8 XCD x 16
    const int flat = (int)blockIdx.x;             // 0..127
    const int k8   = flat & 7;
    const int m    = flat >> 3;                   // 0..15
    const int bm   = (k8 * 4 + (m >> 2)) * 256;
    const int bn   = (m & 3) * 256;

    const unsigned short* Abase = Ain + (size_t)bm * DM;
    const unsigned short* Bbase = W   + (size_t)bn * DM;

    const int srow = 8 * w + (lane >> 3);
    const int scb  = (lane & 7) * 16;
    const int ssc  = scb ^ ((srow & 7) << 4);

    f32x4 acc[8][4];
#pragma unroll
    for (int i = 0; i < 8; i++)
#pragma unroll
        for (int j = 0; j < 4; j++)
            acc[i][j] = f32x4{0.f, 0.f, 0.f, 0.f};

    auto stage_tile = [&](int buf, int kt) {
        const int kc = kt * 64;
#pragma unroll
        for (int q = 0; q < 2; q++) {
            const int r  = srow + 64 * q;
            const int ld = (64 * q + 8 * w) * 64;
            GLD_LDS16(&Abase[(size_t)(r      ) * DM + kc + (ssc >> 1)], &Alds[buf][ld]);
            GLD_LDS16(&Abase[(size_t)(r + 128) * DM + kc + (ssc >> 1)], &Alds[buf][ld + 128 * 64]);
            GLD_LDS16(&Bbase[(size_t)(r      ) * DM + kc + (ssc >> 1)], &Blds[buf][ld]);
            GLD_LDS16(&Bbase[(size_t)(r + 128) * DM + kc + (ssc >> 1)], &Blds[buf][ld + 128 * 64]);
        }
    };

    stage_tile(0, 0);
    asm volatile("s_waitcnt vmcnt(0)" ::: "memory");
    __builtin_amdgcn_s_barrier();
    asm volatile("" ::: "memory");

    for (int T = 0; T < NKT; ++T) {
        const int cur = T & 1;
        if (T < NKT - 1) stage_tile(cur ^ 1, T + 1);

        const unsigned short* A = &Alds[cur][0];
        const unsigned short* B = &Blds[cur][0];
        const int aR0 = wr * 128 + l15;
        const int bR0 = wc * 64 + l15;

        bf16x8 aR[4][2], b01[2][2], b23[2][2];
#pragma unroll
        for (int mi = 0; mi < 4; mi++) {
            aR[mi][0] = lds_frag(A, aR0 + mi * 16, quad * 16);
            aR[mi][1] = lds_frag(A, aR0 + mi * 16, quad * 16 + 64);
        }
#pragma unroll
        for (int nj = 0; nj < 2; nj++) {
            b01[nj][0] = lds_frag(B, bR0 + nj * 16, quad * 16);
            b01[nj][1] = lds_frag(B, bR0 + nj * 16, quad * 16 + 64);
        }
        __builtin_amdgcn_s_setprio(1);
#pragma unroll
        for (int mi = 0; mi < 4; mi++)
#pragma unroll
            for (int nj = 0; nj < 2; nj++) {
                acc[mi][nj] = __builtin_amdgcn_mfma_f32_16x16x32_bf16(aR[mi][0], b01[nj][0], acc[mi][nj], 0, 0, 0);
                acc[mi][nj] = __builtin_amdgcn_mfma_f32_16x16x32_bf16(aR[mi][1], b01[nj][1], acc[mi][nj], 0, 0, 0);
            }
        __builtin_amdgcn_s_setprio(0);
#pragma unroll
        for (int nj = 0; nj < 2; nj++) {
            b23[nj][0] = lds_frag(B, bR0 + (nj + 2) * 16, quad * 16);
            b23[nj][1] = lds_frag(B, bR0 + (nj + 2) * 16, quad * 16 + 64);
        }
        __builtin_amdgcn_s_setprio(1);
#pragma unroll
        for (int mi = 0; mi < 4; mi++)
#pragma unroll
            for (int nj = 0; nj < 2; nj++) {
                acc[mi][nj + 2] = __builtin_amdgcn_mfma_f32_16x16x32_bf16(aR[mi][0], b23[nj][0], acc[mi][nj + 2], 0, 0, 0);
                acc[mi][nj + 2] = __builtin_amdgcn_mfma_f32_16x16x32_bf16(aR[mi][1], b23[nj][1], acc[mi][nj + 2], 0, 0, 0);
            }
        __builtin_amdgcn_s_setprio(0);
#pragma unroll
        for (int mi = 0; mi < 4; mi++) {
            aR[mi][0] = lds_frag(A, aR0 + (mi + 4) * 16, quad * 16);
            aR[mi][1] = lds_frag(A, aR0 + (mi + 4) * 16, quad * 16 + 64);
        }
        __builtin_amdgcn_s_setprio(1);
#pragma unroll
        for (int mi = 0; mi < 4; mi++)
#pragma unroll
            for (int nj = 0; nj < 2; nj++) {
                acc[mi + 4][nj + 2] = __builtin_amdgcn_mfma_f32_16x16x32_bf16(aR[mi][0], b23[nj][0], acc[mi + 4][nj + 2], 0, 0, 0);
                acc[mi + 4][nj + 2] = __builtin_amdgcn_mfma_f32_16x16x32_bf16(aR[mi][1], b23[nj][1], acc[mi + 4][nj + 2], 0, 0, 0);
            }
#pragma unroll
        for (int mi = 0; mi < 4; mi++)
#pragma unroll
            for (int nj = 0; nj < 2; nj++) {
                acc[mi + 4][nj] = __builtin_amdgcn_mfma_f32_16x16x32_bf16(aR[mi][0], b01[nj][0], acc[mi + 4][nj], 0, 0, 0);
                acc[mi + 4][nj] = __builtin_amdgcn_mfma_f32_16x16x32_bf16(aR[mi][1], b01[nj][1], acc[mi + 4][nj], 0, 0, 0);
            }
        __builtin_amdgcn_s_setprio(0);

        asm volatile("s_waitcnt vmcnt(0)" ::: "memory");
        __builtin_amdgcn_s_barrier();
        asm volatile("" ::: "memory");
    }

    const int flag = *flagp;
    float*          outf = (float*)outv;
    unsigned short* outh = (unsigned short*)outv;
#pragma unroll
    for (int nj = 0; nj < 4; nj++) {
        const int   e    = bn + wc * 64 + nj * 16 + l15;
        const float bias = bf2f(bo[e]);
#pragma unroll
        for (int mi = 0; mi < 8; mi++) {
#pragma unroll
            for (int r = 0; r < 4; r++) {
                const int   mrow = bm + wr * 128 + mi * 16 + quad * 4 + r;
                const float v = acc[mi][nj][r] + bias;
                if (flag) outf[(size_t)mrow * DM + e] = v;
                else      outh[(size_t)mrow * DM + e] = f2bf(v);
            }
        }
    }
}

// ---------------------------------------------------------------------------
extern "C" void kernel_launch(void* const* d_in, const int* in_sizes, int n_in,
                              void* d_out, int out_size, void* d_ws, size_t ws_size,
                              hipStream_t stream) {
    // Bind inputs by ELEMENT COUNT (dtype/mask-presence robust)
    const void* x = nullptr;
    const void* Wsrc[4] = {nullptr, nullptr, nullptr, nullptr};
    const void* bsrc[4] = {nullptr, nullptr, nullptr, nullptr};
    int nw = 0, nb = 0;
    for (int i = 0; i < n_in; i++) {
        const int sz = in_sizes[i];
        if (sz == Bz * Sz * DM)            { if (!x) x = d_in[i]; }
        else if (sz == DM * DM)            { if (nw < 4) Wsrc[nw++] = d_in[i]; }
        else if (sz == DM)                 { if (nb < 4) bsrc[nb++] = d_in[i]; }
    }

    char* wsb = (char*)d_ws;
    int*  flagp = (int*)wsb;
    unsigned short* Xc  = (unsigned short*)(wsb + 16);
    const size_t NX = (size_t)Bz * Sz * DM;       // 8,388,608
    const size_t NW = (size_t)DM * DM;            // 1,048,576
    unsigned short* Wc0 = Xc  + NX;
    unsigned short* Wc1 = Wc0 + NW;
    unsigned short* Wc2 = Wc1 + NW;
    unsigned short* Wc3 = Wc2 + NW;
    unsigned short* bc0 = Wc3 + NW;
    unsigned short* bc1 = bc0 + DM;
    unsigned short* bc2 = bc1 + DM;
    unsigned short* bc3 = bc2 + DM;
    unsigned short* Qb  = bc3 + DM;
    const size_t SZ = (size_t)Bz * NH * Sz * DH;  // 8,388,608
    unsigned short* Kb  = Qb  + SZ;
    unsigned short* Vtb = Kb  + SZ;
    unsigned short* AOb = Vtb + SZ;

    detect_dtype<<<1, 64, 0, stream>>>((const unsigned short*)x, flagp);
    convert_inputs<<<dim3(512, 9), 256, 0, stream>>>(
        x, Wsrc[0], Wsrc[1], Wsrc[2], Wsrc[3],
        bsrc[0], bsrc[1], bsrc[2], bsrc[3],
        Xc, Wc0, Wc1, Wc2, Wc3, bc0, bc1, bc2, bc3, flagp);

    gemm_qkv <<<dim3(384), 512, 0, stream>>>(Xc, Wc0, Wc1, Wc2, bc0, bc1, bc2, Qb, Kb, Vtb);
    flash_attn<<<dim3(8, 64), 512, 0, stream>>>(Qb, Kb, Vtb, AOb);
    gemm_out <<<dim3(128), 512, 0, stream>>>(AOb, Wc3, bc3, d_out, flagp);
}